// Round 16
// baseline (83.723 us; speedup 1.0000x reference)
//
#include <hip/hip_runtime.h>
#include <hip/hip_bf16.h>

// Linear attention, fp32. N=8, L=S=8192, H=8, D=Dv=32.
// out[n,l,h,v] = (sum_d phiQ[l,d]*KV[d][v]) * 1/(sum_d phiQ[l,d]*Ksum[d] + 1e-6)
// where KV[d][v] = sum_s phiK[s,d]*values[s,v]  (the /S and *S of the reference
// cancel exactly: S is a power of two).
//
// R16: MEASUREMENT ROUND. R12-R15 plateaued at ~63us with the phase1/phase2
// split unknown (rocprof dispatch durs provably inflated; cross-round
// subtraction contradictory; counter-guided fixes null). This round = R14
// verbatim, but la_phase1 launched TWICE in the deterministic path
// (idempotent overwrite of partials -> output identical). Timed total vs
// R14's 63.0 gives p1 directly: total-63 = p1(L3-warm). Decision rule:
// ~85 -> p1 at floor, attack phase2 next; ~68 -> phase2 is everything.
// R15's persistent phase2 (+7us) is reverted: phase2 wants TLP.

#define N_      8
#define L_      8192
#define S_      8192
#define H_      8
#define D_      32
#define NH_     64            // N*H
#define CH1_    16            // phase-1 s-chunks per (n,h)
#define SPC1_   512           // s per phase-1 block
#define STR1_   36            // u32 row stride (144B: 16B-aligned, shift 4)
#define KVE_    (D_ * D_)     // 1024
#define PKS_    (KVE_ + D_)   // 1056 floats: KV + Ksum

typedef short short8 __attribute__((ext_vector_type(8)));
typedef float f32x4  __attribute__((ext_vector_type(4)));

__device__ __forceinline__ float phi_f(float x) {
    // elu(x)+1 : x>0 -> x+1 ; else exp(x)
    return x > 0.f ? x + 1.f : __expf(x);
}

__device__ __forceinline__ unsigned short bf16_bits(float x) {
    __hip_bfloat16 h = __float2bfloat16(x);   // RNE
    unsigned short u;
    __builtin_memcpy(&u, &h, 2);
    return u;
}

__device__ __forceinline__ void split_bf16(float x, short& hi, short& lo) {
    __hip_bfloat16 hb = __float2bfloat16(x);        // RNE
    const float xh = __bfloat162float(hb);
    __hip_bfloat16 lb = __float2bfloat16(x - xh);
    __builtin_memcpy(&hi, &hb, 2);
    __builtin_memcpy(&lo, &lb, 2);
}

// ---------------- Phase 1: C[32d x 32v] = phiK^T . V per (n,h,chunk) --------
// (R14 version: MFMA, single-bf16 K/V, exact fp32 Ksum, g^=row>>3 swizzle.)
template <bool ATOMIC>
__global__ __launch_bounds__(256) void la_phase1(
    const float* __restrict__ keys, const float* __restrict__ values,
    float* __restrict__ outp /* ATOMIC ? kvfinal[NH][PKS] : partials[NH][CH1][PKS] */)
{
    __shared__ unsigned kS[2][32][STR1_];
    __shared__ unsigned vS[2][32][STR1_];
    __shared__ float red_ks[4][8][4];
    const int nh = blockIdx.x, chunk = blockIdx.y;
    const int n = nh >> 3, h = nh & 7;
    const int t = threadIdx.x, lane = t & 63, w = t >> 6;
    const int row8 = t >> 3;           // 0..31 (s-row within tile half)
    const int c4   = t & 7;            // float4 column (4 d's / 4 v's)
    const int row_l = lane & 15, kg = lane >> 4;
    const int dt = w >> 1, vt = w & 1; // wave's C-tile
    const int odd = row8 & 1;
    const int dv0 = (c4 << 2) + (odd ? 2 : 0);   // first of 2 owned d-rows
    const int s2lo = row8 >> 1;                  // u32 s-pair index (lo half)
    const float* kb = keys   + ((size_t)n * S_) * 256 + h * 32 + (c4 << 2);
    const float* vb = values + ((size_t)n * S_) * 256 + h * 32 + (c4 << 2);
    const int s0 = chunk * SPC1_;

    float ks4[4] = {0.f, 0.f, 0.f, 0.f};
    f32x4 cacc = {0.f, 0.f, 0.f, 0.f};
    float4 Lka, Lkb, Lva, Lvb;

    auto LOADT = [&](int tb) {
        const size_t g0 = ((size_t)(s0 + (tb << 6) + row8)) << 8;
        const size_t g1 = ((size_t)(s0 + (tb << 6) + row8 + 32)) << 8;
        Lka = *(const float4*)(kb + g0);
        Lkb = *(const float4*)(kb + g1);
        Lva = *(const float4*)(vb + g0);
        Lvb = *(const float4*)(vb + g1);
    };
    auto STORE4 = [&](unsigned (*Sarr)[STR1_], const unsigned short* x, int s2) {
        const unsigned mA = (unsigned)x[0] | ((unsigned)x[1] << 16);
        const unsigned mB = (unsigned)x[2] | ((unsigned)x[3] << 16);
        const unsigned pA = __shfl_xor(mA, 8);
        const unsigned pB = __shfl_xor(mB, 8);
        const unsigned m = odd ? mB : mA, p = odd ? pB : pA;
        const unsigned se = odd ? p : m;          // s-even's two bf16 (j, j+1)
        const unsigned so = odd ? m : p;          // s-odd's
        const unsigned w0 = (se & 0xffffu) | ((so & 0xffffu) << 16);
        const unsigned w1 = (se >> 16) | (so & 0xffff0000u);
        Sarr[dv0][4 * ((s2 >> 2) ^ (dv0 >> 3)) + (s2 & 3)]           = w0;
        Sarr[dv0 + 1][4 * ((s2 >> 2) ^ ((dv0 + 1) >> 3)) + (s2 & 3)] = w1;
    };
    auto PROCT = [&](int buf) {
        const float f0[4] = {phi_f(Lka.x), phi_f(Lka.y), phi_f(Lka.z), phi_f(Lka.w)};
        const float f1[4] = {phi_f(Lkb.x), phi_f(Lkb.y), phi_f(Lkb.z), phi_f(Lkb.w)};
        unsigned short kx[4], ky[4], vx[4], vy[4];
#pragma unroll
        for (int j = 0; j < 4; ++j) ks4[j] += f0[j] + f1[j];
        kx[0] = bf16_bits(f0[0]); kx[1] = bf16_bits(f0[1]);
        kx[2] = bf16_bits(f0[2]); kx[3] = bf16_bits(f0[3]);
        ky[0] = bf16_bits(f1[0]); ky[1] = bf16_bits(f1[1]);
        ky[2] = bf16_bits(f1[2]); ky[3] = bf16_bits(f1[3]);
        vx[0] = bf16_bits(Lva.x); vx[1] = bf16_bits(Lva.y);
        vx[2] = bf16_bits(Lva.z); vx[3] = bf16_bits(Lva.w);
        vy[0] = bf16_bits(Lvb.x); vy[1] = bf16_bits(Lvb.y);
        vy[2] = bf16_bits(Lvb.z); vy[3] = bf16_bits(Lvb.w);
        STORE4(kS[buf], kx, s2lo);
        STORE4(kS[buf], ky, s2lo + 16);
        STORE4(vS[buf], vx, s2lo);
        STORE4(vS[buf], vy, s2lo + 16);
    };
    auto FRAG = [&](const unsigned (*Sarr)[STR1_], int row, int sh) -> short8 {
        const int g = ((sh << 2) | kg) ^ (row >> 3);
        union { uint4 u; short8 s; } U;
        U.u = *(const uint4*)&Sarr[row][g << 2];
        return U.s;
    };
    auto COMPT = [&](int buf) {
#pragma unroll
        for (int sh = 0; sh < 2; ++sh) {
            const short8 A = FRAG(kS[buf], (dt << 4) + row_l, sh);
            const short8 B = FRAG(vS[buf], (vt << 4) + row_l, sh);
            cacc = __builtin_amdgcn_mfma_f32_16x16x32_bf16(A, B, cacc, 0, 0, 0);
        }
    };

    LOADT(0);
    PROCT(0);
    __syncthreads();
#pragma unroll
    for (int tb = 0; tb < 8; ++tb) {
        const int cur = tb & 1;
        if (tb < 7) LOADT(tb + 1);       // next-tile loads in flight (T14)
        COMPT(cur);
        if (tb < 7) PROCT(cur ^ 1);      // waits vmcnt, stages other buffer
        __syncthreads();
    }

    // ksum: butterfly over lane bits 3..5 (8 same-c4 lanes), then cross-wave
#pragma unroll
    for (int j = 0; j < 4; ++j) {
        float x = ks4[j];
        x += __shfl_xor(x, 8);
        x += __shfl_xor(x, 16);
        x += __shfl_xor(x, 32);
        ks4[j] = x;
    }
    if (lane < 8) {
#pragma unroll
        for (int j = 0; j < 4; ++j) red_ks[w][lane][j] = ks4[j];
    }
    __syncthreads();

    if (ATOMIC) {
        float* p = outp + (size_t)nh * PKS_;
#pragma unroll
        for (int r = 0; r < 4; ++r) {
            const int dd = (dt << 4) + (kg << 2) + r;   // D row = (lane>>4)*4+reg
            const int vv = (vt << 4) + row_l;           // D col = lane&15
            atomicAdd(&p[dd * D_ + vv], cacc[r]);
        }
        if (t < 32) {
            const float s = red_ks[0][t >> 2][t & 3] + red_ks[1][t >> 2][t & 3]
                          + red_ks[2][t >> 2][t & 3] + red_ks[3][t >> 2][t & 3];
            atomicAdd(&p[KVE_ + t], s);
        }
    } else {
        float* p = outp + ((size_t)nh * CH1_ + chunk) * PKS_;
#pragma unroll
        for (int r = 0; r < 4; ++r) {
            const int dd = (dt << 4) + (kg << 2) + r;
            const int vv = (vt << 4) + row_l;
            p[dd * D_ + vv] = cacc[r];
        }
        if (t < 32) {
            p[KVE_ + t] = red_ks[0][t >> 2][t & 3] + red_ks[1][t >> 2][t & 3]
                        + red_ks[2][t >> 2][t & 3] + red_ks[3][t >> 2][t & 3];
        }
    }
}

// ---- Phase 1b: deterministic 16-way reduce + split-bf16 transpose ----
__global__ __launch_bounds__(256) void la_reduce(
    const float* __restrict__ partials,
    short* __restrict__ kvThi, short* __restrict__ kvTlo,
    float* __restrict__ ksumf)
{
    const int nh = blockIdx.x;
    for (int e = threadIdx.x; e < PKS_; e += 256) {
        const float* p = partials + (size_t)nh * CH1_ * PKS_ + e;
        float s = 0.f;
#pragma unroll
        for (int c = 0; c < CH1_; ++c) s += p[(size_t)c * PKS_];
        if (e < KVE_) {
            const int d = e >> 5, v = e & 31;
            short hi, lo; split_bf16(s, hi, lo);
            kvThi[nh * KVE_ + v * D_ + d] = hi;
            kvTlo[nh * KVE_ + v * D_ + d] = lo;
        } else {
            ksumf[nh * D_ + (e - KVE_)] = s;
        }
    }
}

// atomic-path variant: same split/transpose from a finished kvf buffer
__global__ __launch_bounds__(256) void la_convert(
    const float* __restrict__ kvf,
    short* __restrict__ kvThi, short* __restrict__ kvTlo,
    float* __restrict__ ksumf)
{
    const int nh = blockIdx.x;
    for (int e = threadIdx.x; e < PKS_; e += 256) {
        const float s = kvf[(size_t)nh * PKS_ + e];
        if (e < KVE_) {
            const int d = e >> 5, v = e & 31;
            short hi, lo; split_bf16(s, hi, lo);
            kvThi[nh * KVE_ + v * D_ + d] = hi;
            kvTlo[nh * KVE_ + v * D_ + d] = lo;
        } else {
            ksumf[nh * D_ + (e - KVE_)] = s;
        }
    }
}

__global__ void la_zero(float* __restrict__ p, int nelem) {
    const int i = blockIdx.x * 256 + threadIdx.x;
    if (i < nelem) p[i] = 0.f;
}

// ---------------- Phase 2: MFMA split-bf16 (R14 one-shot version) ----------
// Wave-task = (16-row tile, h): C[16x32] = phiQ[16x32] @ KV[32x32] via
// 2 v-tiles x 3 split-term mfma_f32_16x16x32_bf16. A-frag: row=lane&15,
// k=(lane>>4)*8+e (any k-permutation cancels: A,B share the mapping).
// D (m89-verified): col=lane&15, row=(lane>>4)*4+reg. dot on fp32 VALU.
__global__ __launch_bounds__(256) void la_phase2(
    const float* __restrict__ queries,
    const short* __restrict__ kvThi, const short* __restrict__ kvTlo,
    const float* __restrict__ ksumf, float* __restrict__ out)
{
    const int t = threadIdx.x, lane = t & 63, w = t >> 6;
    const int wt = blockIdx.x * 4 + w;      // 0..32767
    const int h  = wt & 7;
    const int rt = wt >> 3;                 // 16-row tile id, 0..4095
    const size_t rowg0 = (size_t)rt * 16;   // global (n,l)-row base
    const int n = (int)(rowg0 >> 13);
    const int nh = n * 8 + h;
    const int row_l = lane & 15;            // A-row / B-col
    const int kg    = lane >> 4;            // k-group: k = kg*8 + e

    // ---- A: load 8 fp32 q, phi, keep fp32 for dot, split to bf16 hi/lo ----
    const float* qp = queries + (rowg0 + row_l) * 256 + h * D_ + kg * 8;
    float qa[8];
    {
        const float4 qA = *(const float4*)(qp);
        const float4 qB = *(const float4*)(qp + 4);
        qa[0] = phi_f(qA.x); qa[1] = phi_f(qA.y); qa[2] = phi_f(qA.z); qa[3] = phi_f(qA.w);
        qa[4] = phi_f(qB.x); qa[5] = phi_f(qB.y); qa[6] = phi_f(qB.z); qa[7] = phi_f(qB.w);
    }
    short8 ahi, alo;
#pragma unroll
    for (int e = 0; e < 8; ++e) {
        short hs, ls; split_bf16(qa[e], hs, ls);
        ahi[e] = hs; alo[e] = ls;
    }

    // ---- B: one short8 per (vtile, hi/lo) from transposed bf16 KV ----
    const short* bh = kvThi + (size_t)nh * KVE_;
    const short* bl = kvTlo + (size_t)nh * KVE_;
    const short8 bh0 = *(const short8*)(bh + (row_l     ) * D_ + kg * 8);
    const short8 bh1 = *(const short8*)(bh + (row_l + 16) * D_ + kg * 8);
    const short8 bl0 = *(const short8*)(bl + (row_l     ) * D_ + kg * 8);
    const short8 bl1 = *(const short8*)(bl + (row_l + 16) * D_ + kg * 8);

    // ---- 6 MFMAs: C = Alo*Bhi + Ahi*Blo + Ahi*Bhi (fp32 accum) ----
    f32x4 c0 = {0.f, 0.f, 0.f, 0.f}, c1 = {0.f, 0.f, 0.f, 0.f};
    c0 = __builtin_amdgcn_mfma_f32_16x16x32_bf16(alo, bh0, c0, 0, 0, 0);
    c0 = __builtin_amdgcn_mfma_f32_16x16x32_bf16(ahi, bl0, c0, 0, 0, 0);
    c0 = __builtin_amdgcn_mfma_f32_16x16x32_bf16(ahi, bh0, c0, 0, 0, 0);
    c1 = __builtin_amdgcn_mfma_f32_16x16x32_bf16(alo, bh1, c1, 0, 0, 0);
    c1 = __builtin_amdgcn_mfma_f32_16x16x32_bf16(ahi, bl1, c1, 0, 0, 0);
    c1 = __builtin_amdgcn_mfma_f32_16x16x32_bf16(ahi, bh1, c1, 0, 0, 0);

    // ---- dot = phiQ . Ksum in fp32; reduce the 4 k-groups per row ----
    const float* ksp = ksumf + nh * D_ + kg * 8;
    float dt;
    {
        const float4 kA = *(const float4*)(ksp);
        const float4 kB = *(const float4*)(ksp + 4);
        dt = qa[0] * kA.x;
        dt = fmaf(qa[1], kA.y, dt); dt = fmaf(qa[2], kA.z, dt);
        dt = fmaf(qa[3], kA.w, dt); dt = fmaf(qa[4], kB.x, dt);
        dt = fmaf(qa[5], kB.y, dt); dt = fmaf(qa[6], kB.z, dt);
        dt = fmaf(qa[7], kB.w, dt);
    }
    dt += __shfl_xor(dt, 16);
    dt += __shfl_xor(dt, 32);   // all lanes now hold dot[row_l]

    // ---- normalize + store: row' = kg*4 + r, col = row_l (m89 layout) ----
    float* ob = out + rowg0 * 256 + h * D_ + row_l;
#pragma unroll
    for (int r = 0; r < 4; ++r) {
        const int rowp = kg * 4 + r;
        const float drow = __shfl(dt, rowp);          // lane rowp holds dot[rowp]
        const float z = __builtin_amdgcn_rcpf(drow + 1e-6f);
        ob[(size_t)rowp * 256]      = c0[r] * z;
        ob[(size_t)rowp * 256 + 16] = c1[r] * z;
    }
}

extern "C" void kernel_launch(void* const* d_in, const int* in_sizes, int n_in,
                              void* d_out, int out_size, void* d_ws, size_t ws_size,
                              hipStream_t stream)
{
    const float* queries = (const float*)d_in[0];
    const float* keys    = (const float*)d_in[1];
    const float* values  = (const float*)d_in[2];
    float* out = (float*)d_out;
    float* ws  = (float*)d_ws;

    const size_t partial_elems = (size_t)NH_ * CH1_ * PKS_;    // 1,081,344 floats
    const size_t split_elems   = (size_t)NH_ * KVE_;           // per hi/lo, in shorts
    const size_t split_floats  = split_elems / 2;              // 32,768 float-slots each
    const size_t ksum_floats   = (size_t)NH_ * D_;             // 2,048
    const dim3 blk(256);
    const int p2_blocks = (N_ * L_ * H_) / 16 / 4;             // 8192

    if (ws_size >= (partial_elems + 2 * split_floats + ksum_floats) * sizeof(float)) {
        // deterministic two-stage reduction + split-bf16 conversion
        float* partials = ws;
        short* kvThi = (short*)(ws + partial_elems);
        short* kvTlo = kvThi + split_elems;
        float* ksumf = (float*)(kvTlo + split_elems);
        // MEASUREMENT: phase1 launched twice (idempotent overwrite of
        // partials; output unchanged). Timed total - 63.0 = p1 cost.
        la_phase1<false><<<dim3(NH_, CH1_), blk, 0, stream>>>(keys, values, partials);
        la_phase1<false><<<dim3(NH_, CH1_), blk, 0, stream>>>(keys, values, partials);
        la_reduce<<<dim3(NH_), blk, 0, stream>>>(partials, kvThi, kvTlo, ksumf);
        la_phase2<<<dim3(p2_blocks), blk, 0, stream>>>(queries, kvThi, kvTlo, ksumf, out);
    } else {
        // fallback: atomic accumulation into zeroed kvf, then convert
        float* kvf = ws;
        short* kvThi = (short*)(ws + (size_t)NH_ * PKS_);
        short* kvTlo = kvThi + split_elems;
        float* ksumf = (float*)(kvTlo + split_elems);
        const int nz = (int)((size_t)NH_ * PKS_);
        la_zero<<<dim3((nz + 255) / 256), blk, 0, stream>>>(kvf, nz);
        la_phase1<true><<<dim3(NH_, CH1_), blk, 0, stream>>>(keys, values, kvf);
        la_convert<<<dim3(NH_), blk, 0, stream>>>(kvf, kvThi, kvTlo, ksumf);
        la_phase2<<<dim3(p2_blocks), blk, 0, stream>>>(queries, kvThi, kvTlo, ksumf, out);
    }
}

// Round 17
// 66.753 us; speedup vs baseline: 1.2542x; 1.2542x over previous
//
#include <hip/hip_runtime.h>
#include <hip/hip_bf16.h>

// Linear attention, fp32. N=8, L=S=8192, H=8, D=Dv=32.
// out[n,l,h,v] = (sum_d phiQ[l,d]*KV[d][v]) * 1/(sum_d phiQ[l,d]*Ksum[d] + 1e-6)
// where KV[d][v] = sum_s phiK[s,d]*values[s,v]  (the /S and *S of the reference
// cancel exactly: S is a power of two).
//
// R17: phase2 latency amortization. R16 measurement: p1 = 20.7us (= its HBM
// floor), reduce ~1-2, phase2 ~40 vs ~15-20 floor -> phase2 is the only
// target left. Its one-shot waves had prefetch depth 0 (B ~300cyc + Q
// ~500-900cyc serial per task); R15's 8-deep loop over-corrected (depth-1
// prefetch can't cover HBM). Midpoint: 2 row-tiles/wave, BOTH Q tiles
// front-loaded (depth-2, in flight together), B loaded once (2x amortized),
// 16384 waves keep TLP. Pair-preserving XCD swizzle: even/odd block pairs
// sharing the same 32 Q rows stay on one XCD's L2 (T1, bijective).
// Phase1 = R14 (MFMA, at floor). absmax expected unchanged (2.44e-4).

#define N_      8
#define L_      8192
#define S_      8192
#define H_      8
#define D_      32
#define NH_     64            // N*H
#define CH1_    16            // phase-1 s-chunks per (n,h)
#define SPC1_   512           // s per phase-1 block
#define STR1_   36            // u32 row stride (144B: 16B-aligned, shift 4)
#define KVE_    (D_ * D_)     // 1024
#define PKS_    (KVE_ + D_)   // 1056 floats: KV + Ksum

typedef short short8 __attribute__((ext_vector_type(8)));
typedef float f32x4  __attribute__((ext_vector_type(4)));

__device__ __forceinline__ float phi_f(float x) {
    // elu(x)+1 : x>0 -> x+1 ; else exp(x)
    return x > 0.f ? x + 1.f : __expf(x);
}

__device__ __forceinline__ unsigned short bf16_bits(float x) {
    __hip_bfloat16 h = __float2bfloat16(x);   // RNE
    unsigned short u;
    __builtin_memcpy(&u, &h, 2);
    return u;
}

__device__ __forceinline__ void split_bf16(float x, short& hi, short& lo) {
    __hip_bfloat16 hb = __float2bfloat16(x);        // RNE
    const float xh = __bfloat162float(hb);
    __hip_bfloat16 lb = __float2bfloat16(x - xh);
    __builtin_memcpy(&hi, &hb, 2);
    __builtin_memcpy(&lo, &lb, 2);
}

// ---------------- Phase 1: C[32d x 32v] = phiK^T . V per (n,h,chunk) --------
// (R14 version: MFMA, single-bf16 K/V, exact fp32 Ksum, g^=row>>3 swizzle.)
template <bool ATOMIC>
__global__ __launch_bounds__(256) void la_phase1(
    const float* __restrict__ keys, const float* __restrict__ values,
    float* __restrict__ outp /* ATOMIC ? kvfinal[NH][PKS] : partials[NH][CH1][PKS] */)
{
    __shared__ unsigned kS[2][32][STR1_];
    __shared__ unsigned vS[2][32][STR1_];
    __shared__ float red_ks[4][8][4];
    const int nh = blockIdx.x, chunk = blockIdx.y;
    const int n = nh >> 3, h = nh & 7;
    const int t = threadIdx.x, lane = t & 63, w = t >> 6;
    const int row8 = t >> 3;           // 0..31 (s-row within tile half)
    const int c4   = t & 7;            // float4 column (4 d's / 4 v's)
    const int row_l = lane & 15, kg = lane >> 4;
    const int dt = w >> 1, vt = w & 1; // wave's C-tile
    const int odd = row8 & 1;
    const int dv0 = (c4 << 2) + (odd ? 2 : 0);   // first of 2 owned d-rows
    const int s2lo = row8 >> 1;                  // u32 s-pair index (lo half)
    const float* kb = keys   + ((size_t)n * S_) * 256 + h * 32 + (c4 << 2);
    const float* vb = values + ((size_t)n * S_) * 256 + h * 32 + (c4 << 2);
    const int s0 = chunk * SPC1_;

    float ks4[4] = {0.f, 0.f, 0.f, 0.f};
    f32x4 cacc = {0.f, 0.f, 0.f, 0.f};
    float4 Lka, Lkb, Lva, Lvb;

    auto LOADT = [&](int tb) {
        const size_t g0 = ((size_t)(s0 + (tb << 6) + row8)) << 8;
        const size_t g1 = ((size_t)(s0 + (tb << 6) + row8 + 32)) << 8;
        Lka = *(const float4*)(kb + g0);
        Lkb = *(const float4*)(kb + g1);
        Lva = *(const float4*)(vb + g0);
        Lvb = *(const float4*)(vb + g1);
    };
    auto STORE4 = [&](unsigned (*Sarr)[STR1_], const unsigned short* x, int s2) {
        const unsigned mA = (unsigned)x[0] | ((unsigned)x[1] << 16);
        const unsigned mB = (unsigned)x[2] | ((unsigned)x[3] << 16);
        const unsigned pA = __shfl_xor(mA, 8);
        const unsigned pB = __shfl_xor(mB, 8);
        const unsigned m = odd ? mB : mA, p = odd ? pB : pA;
        const unsigned se = odd ? p : m;          // s-even's two bf16 (j, j+1)
        const unsigned so = odd ? m : p;          // s-odd's
        const unsigned w0 = (se & 0xffffu) | ((so & 0xffffu) << 16);
        const unsigned w1 = (se >> 16) | (so & 0xffff0000u);
        Sarr[dv0][4 * ((s2 >> 2) ^ (dv0 >> 3)) + (s2 & 3)]           = w0;
        Sarr[dv0 + 1][4 * ((s2 >> 2) ^ ((dv0 + 1) >> 3)) + (s2 & 3)] = w1;
    };
    auto PROCT = [&](int buf) {
        const float f0[4] = {phi_f(Lka.x), phi_f(Lka.y), phi_f(Lka.z), phi_f(Lka.w)};
        const float f1[4] = {phi_f(Lkb.x), phi_f(Lkb.y), phi_f(Lkb.z), phi_f(Lkb.w)};
        unsigned short kx[4], ky[4], vx[4], vy[4];
#pragma unroll
        for (int j = 0; j < 4; ++j) ks4[j] += f0[j] + f1[j];
        kx[0] = bf16_bits(f0[0]); kx[1] = bf16_bits(f0[1]);
        kx[2] = bf16_bits(f0[2]); kx[3] = bf16_bits(f0[3]);
        ky[0] = bf16_bits(f1[0]); ky[1] = bf16_bits(f1[1]);
        ky[2] = bf16_bits(f1[2]); ky[3] = bf16_bits(f1[3]);
        vx[0] = bf16_bits(Lva.x); vx[1] = bf16_bits(Lva.y);
        vx[2] = bf16_bits(Lva.z); vx[3] = bf16_bits(Lva.w);
        vy[0] = bf16_bits(Lvb.x); vy[1] = bf16_bits(Lvb.y);
        vy[2] = bf16_bits(Lvb.z); vy[3] = bf16_bits(Lvb.w);
        STORE4(kS[buf], kx, s2lo);
        STORE4(kS[buf], ky, s2lo + 16);
        STORE4(vS[buf], vx, s2lo);
        STORE4(vS[buf], vy, s2lo + 16);
    };
    auto FRAG = [&](const unsigned (*Sarr)[STR1_], int row, int sh) -> short8 {
        const int g = ((sh << 2) | kg) ^ (row >> 3);
        union { uint4 u; short8 s; } U;
        U.u = *(const uint4*)&Sarr[row][g << 2];
        return U.s;
    };
    auto COMPT = [&](int buf) {
#pragma unroll
        for (int sh = 0; sh < 2; ++sh) {
            const short8 A = FRAG(kS[buf], (dt << 4) + row_l, sh);
            const short8 B = FRAG(vS[buf], (vt << 4) + row_l, sh);
            cacc = __builtin_amdgcn_mfma_f32_16x16x32_bf16(A, B, cacc, 0, 0, 0);
        }
    };

    LOADT(0);
    PROCT(0);
    __syncthreads();
#pragma unroll
    for (int tb = 0; tb < 8; ++tb) {
        const int cur = tb & 1;
        if (tb < 7) LOADT(tb + 1);       // next-tile loads in flight (T14)
        COMPT(cur);
        if (tb < 7) PROCT(cur ^ 1);      // waits vmcnt, stages other buffer
        __syncthreads();
    }

    // ksum: butterfly over lane bits 3..5 (8 same-c4 lanes), then cross-wave
#pragma unroll
    for (int j = 0; j < 4; ++j) {
        float x = ks4[j];
        x += __shfl_xor(x, 8);
        x += __shfl_xor(x, 16);
        x += __shfl_xor(x, 32);
        ks4[j] = x;
    }
    if (lane < 8) {
#pragma unroll
        for (int j = 0; j < 4; ++j) red_ks[w][lane][j] = ks4[j];
    }
    __syncthreads();

    if (ATOMIC) {
        float* p = outp + (size_t)nh * PKS_;
#pragma unroll
        for (int r = 0; r < 4; ++r) {
            const int dd = (dt << 4) + (kg << 2) + r;   // D row = (lane>>4)*4+reg
            const int vv = (vt << 4) + row_l;           // D col = lane&15
            atomicAdd(&p[dd * D_ + vv], cacc[r]);
        }
        if (t < 32) {
            const float s = red_ks[0][t >> 2][t & 3] + red_ks[1][t >> 2][t & 3]
                          + red_ks[2][t >> 2][t & 3] + red_ks[3][t >> 2][t & 3];
            atomicAdd(&p[KVE_ + t], s);
        }
    } else {
        float* p = outp + ((size_t)nh * CH1_ + chunk) * PKS_;
#pragma unroll
        for (int r = 0; r < 4; ++r) {
            const int dd = (dt << 4) + (kg << 2) + r;
            const int vv = (vt << 4) + row_l;
            p[dd * D_ + vv] = cacc[r];
        }
        if (t < 32) {
            p[KVE_ + t] = red_ks[0][t >> 2][t & 3] + red_ks[1][t >> 2][t & 3]
                        + red_ks[2][t >> 2][t & 3] + red_ks[3][t >> 2][t & 3];
        }
    }
}

// ---- Phase 1b: deterministic 16-way reduce + split-bf16 transpose ----
__global__ __launch_bounds__(256) void la_reduce(
    const float* __restrict__ partials,
    short* __restrict__ kvThi, short* __restrict__ kvTlo,
    float* __restrict__ ksumf)
{
    const int nh = blockIdx.x;
    for (int e = threadIdx.x; e < PKS_; e += 256) {
        const float* p = partials + (size_t)nh * CH1_ * PKS_ + e;
        float s = 0.f;
#pragma unroll
        for (int c = 0; c < CH1_; ++c) s += p[(size_t)c * PKS_];
        if (e < KVE_) {
            const int d = e >> 5, v = e & 31;
            short hi, lo; split_bf16(s, hi, lo);
            kvThi[nh * KVE_ + v * D_ + d] = hi;
            kvTlo[nh * KVE_ + v * D_ + d] = lo;
        } else {
            ksumf[nh * D_ + (e - KVE_)] = s;
        }
    }
}

// atomic-path variant: same split/transpose from a finished kvf buffer
__global__ __launch_bounds__(256) void la_convert(
    const float* __restrict__ kvf,
    short* __restrict__ kvThi, short* __restrict__ kvTlo,
    float* __restrict__ ksumf)
{
    const int nh = blockIdx.x;
    for (int e = threadIdx.x; e < PKS_; e += 256) {
        const float s = kvf[(size_t)nh * PKS_ + e];
        if (e < KVE_) {
            const int d = e >> 5, v = e & 31;
            short hi, lo; split_bf16(s, hi, lo);
            kvThi[nh * KVE_ + v * D_ + d] = hi;
            kvTlo[nh * KVE_ + v * D_ + d] = lo;
        } else {
            ksumf[nh * D_ + (e - KVE_)] = s;
        }
    }
}

__global__ void la_zero(float* __restrict__ p, int nelem) {
    const int i = blockIdx.x * 256 + threadIdx.x;
    if (i < nelem) p[i] = 0.f;
}

// ---------------- Phase 2: MFMA split-bf16, 2 row-tiles/wave ----------------
// Wave = (32-row group, h); both 16-row Q tiles front-loaded (depth-2), B +
// Ksum loaded once. Block = 4 waves = 4 h of the same 32 rows; even/odd block
// pairs (h 0-3 / 4-7) share rows -> pair-preserving XCD swizzle keeps them on
// one XCD's L2. D layout (m89): col=lane&15, row=(lane>>4)*4+reg.
__global__ __launch_bounds__(256) void la_phase2(
    const float* __restrict__ queries,
    const short* __restrict__ kvThi, const short* __restrict__ kvTlo,
    const float* __restrict__ ksumf, float* __restrict__ out)
{
    const int t = threadIdx.x, lane = t & 63, w = t >> 6;
    // pair-preserving bijective XCD swizzle over 4096 blocks (2048 pairs)
    const int bx0 = blockIdx.x;
    const int px  = bx0 >> 1;                       // pair id 0..2047
    const int swz = (px & 7) * 256 + (px >> 3);     // 2048/8 = 256 per XCD
    const int bx  = (swz << 1) | (bx0 & 1);
    const int wt  = bx * 4 + w;                     // 0..16383
    const int h   = wt & 7;
    const int rt2 = wt >> 3;                        // 32-row group, 0..2047
    const size_t rowg0 = (size_t)rt2 * 32;
    const int n  = (int)(rowg0 >> 13);
    const int nh = n * 8 + h;
    const int row_l = lane & 15;                    // A-row / B-col
    const int kg    = lane >> 4;                    // k-group: k = kg*8 + e

    // ---- B + Ksum once per wave (L2-hot) ----
    const short* bh = kvThi + (size_t)nh * KVE_;
    const short* bl = kvTlo + (size_t)nh * KVE_;
    const short8 bh0 = *(const short8*)(bh + (row_l     ) * D_ + kg * 8);
    const short8 bh1 = *(const short8*)(bh + (row_l + 16) * D_ + kg * 8);
    const short8 bl0 = *(const short8*)(bl + (row_l     ) * D_ + kg * 8);
    const short8 bl1 = *(const short8*)(bl + (row_l + 16) * D_ + kg * 8);
    const float4 kA = *(const float4*)(ksumf + nh * D_ + kg * 8);
    const float4 kB = *(const float4*)(ksumf + nh * D_ + kg * 8 + 4);

    // ---- both Q tiles issued up front (depth-2, in flight together) ----
    const float* qp0 = queries + (rowg0 + row_l) * 256 + h * D_ + kg * 8;
    const float* qp1 = qp0 + 16 * 256;
    float4 qA[2], qB[2];
    qA[0] = *(const float4*)(qp0);
    qB[0] = *(const float4*)(qp0 + 4);
    qA[1] = *(const float4*)(qp1);
    qB[1] = *(const float4*)(qp1 + 4);

    float* ob0 = out + rowg0 * 256 + h * D_ + row_l;

#pragma unroll
    for (int tt = 0; tt < 2; ++tt) {
        float qa[8];
        qa[0] = phi_f(qA[tt].x); qa[1] = phi_f(qA[tt].y);
        qa[2] = phi_f(qA[tt].z); qa[3] = phi_f(qA[tt].w);
        qa[4] = phi_f(qB[tt].x); qa[5] = phi_f(qB[tt].y);
        qa[6] = phi_f(qB[tt].z); qa[7] = phi_f(qB[tt].w);
        short8 ahi, alo;
#pragma unroll
        for (int e = 0; e < 8; ++e) {
            short hs, ls; split_bf16(qa[e], hs, ls);
            ahi[e] = hs; alo[e] = ls;
        }
        f32x4 c0 = {0.f, 0.f, 0.f, 0.f}, c1 = {0.f, 0.f, 0.f, 0.f};
        c0 = __builtin_amdgcn_mfma_f32_16x16x32_bf16(alo, bh0, c0, 0, 0, 0);
        c0 = __builtin_amdgcn_mfma_f32_16x16x32_bf16(ahi, bl0, c0, 0, 0, 0);
        c0 = __builtin_amdgcn_mfma_f32_16x16x32_bf16(ahi, bh0, c0, 0, 0, 0);
        c1 = __builtin_amdgcn_mfma_f32_16x16x32_bf16(alo, bh1, c1, 0, 0, 0);
        c1 = __builtin_amdgcn_mfma_f32_16x16x32_bf16(ahi, bl1, c1, 0, 0, 0);
        c1 = __builtin_amdgcn_mfma_f32_16x16x32_bf16(ahi, bh1, c1, 0, 0, 0);

        float dt = qa[0] * kA.x;
        dt = fmaf(qa[1], kA.y, dt); dt = fmaf(qa[2], kA.z, dt);
        dt = fmaf(qa[3], kA.w, dt); dt = fmaf(qa[4], kB.x, dt);
        dt = fmaf(qa[5], kB.y, dt); dt = fmaf(qa[6], kB.z, dt);
        dt = fmaf(qa[7], kB.w, dt);
        dt += __shfl_xor(dt, 16);
        dt += __shfl_xor(dt, 32);           // all lanes hold dot[row_l]

        float* ob = ob0 + (size_t)tt * 16 * 256;
#pragma unroll
        for (int r = 0; r < 4; ++r) {
            const int rowp = kg * 4 + r;
            const float drow = __shfl(dt, rowp);
            const float z = __builtin_amdgcn_rcpf(drow + 1e-6f);
            ob[(size_t)rowp * 256]      = c0[r] * z;
            ob[(size_t)rowp * 256 + 16] = c1[r] * z;
        }
    }
}

extern "C" void kernel_launch(void* const* d_in, const int* in_sizes, int n_in,
                              void* d_out, int out_size, void* d_ws, size_t ws_size,
                              hipStream_t stream)
{
    const float* queries = (const float*)d_in[0];
    const float* keys    = (const float*)d_in[1];
    const float* values  = (const float*)d_in[2];
    float* out = (float*)d_out;
    float* ws  = (float*)d_ws;

    const size_t partial_elems = (size_t)NH_ * CH1_ * PKS_;    // 1,081,344 floats
    const size_t split_elems   = (size_t)NH_ * KVE_;           // per hi/lo, in shorts
    const size_t split_floats  = split_elems / 2;              // 32,768 float-slots each
    const size_t ksum_floats   = (size_t)NH_ * D_;             // 2,048
    const dim3 blk(256);
    const int p2_blocks = (N_ * L_ * H_) / 32 / 4;             // 4096

    if (ws_size >= (partial_elems + 2 * split_floats + ksum_floats) * sizeof(float)) {
        // deterministic two-stage reduction + split-bf16 conversion
        float* partials = ws;
        short* kvThi = (short*)(ws + partial_elems);
        short* kvTlo = kvThi + split_elems;
        float* ksumf = (float*)(kvTlo + split_elems);
        la_phase1<false><<<dim3(NH_, CH1_), blk, 0, stream>>>(keys, values, partials);
        la_reduce<<<dim3(NH_), blk, 0, stream>>>(partials, kvThi, kvTlo, ksumf);
        la_phase2<<<dim3(p2_blocks), blk, 0, stream>>>(queries, kvThi, kvTlo, ksumf, out);
    } else {
        // fallback: atomic accumulation into zeroed kvf, then convert
        float* kvf = ws;
        short* kvThi = (short*)(ws + (size_t)NH_ * PKS_);
        short* kvTlo = kvThi + split_elems;
        float* ksumf = (float*)(kvTlo + split_elems);
        const int nz = (int)((size_t)NH_ * PKS_);
        la_zero<<<dim3((nz + 255) / 256), blk, 0, stream>>>(kvf, nz);
        la_phase1<true><<<dim3(NH_, CH1_), blk, 0, stream>>>(keys, values, kvf);
        la_convert<<<dim3(NH_), blk, 0, stream>>>(kvf, kvThi, kvTlo, ksumf);
        la_phase2<<<dim3(p2_blocks), blk, 0, stream>>>(queries, kvThi, kvTlo, ksumf, out);
    }
}

// Round 18
// 62.915 us; speedup vs baseline: 1.3307x; 1.0610x over previous
//
#include <hip/hip_runtime.h>
#include <hip/hip_bf16.h>

// Linear attention, fp32. N=8, L=S=8192, H=8, D=Dv=32.
// out[n,l,h,v] = (sum_d phiQ[l,d]*KV[d][v]) * 1/(sum_d phiQ[l,d]*Ksum[d] + 1e-6)
// where KV[d][v] = sum_s phiK[s,d]*values[s,v]  (the /S and *S of the reference
// cancel exactly: S is a power of two).
//
// R18: phase2 with DENSE per-block streaming. Facts: p1=20.7us (floor,
// measured R16); p2~40 vs ~16-20 floor at ~2.5TB/s effective; TLP dominates
// (32K waves > 16K > 4K across R14/R17/R15). Phase1 proves h-sliced reads
// can hit 6.2TB/s when blocks stream densely. New phase2: block = 512 thr
// (8 waves) x 16 rows; Q staged via LDS as full 1KB rows (block reads 16KB
// contiguous), wave w computes h=w (so block writes the complete 16KB out
// region too); granule swizzle p=g^(row&7) -> 2-way banks both sides (free);
// 4096 blocks x 8 = 32K waves (R14 TLP kept); phi fused in staging
// (bitwise-identical math -> absmax must stay 2.441e-4).
// Phase1 = R14 (MFMA, at floor). Reduce unchanged.

#define N_      8
#define L_      8192
#define S_      8192
#define H_      8
#define D_      32
#define NH_     64            // N*H
#define CH1_    16            // phase-1 s-chunks per (n,h)
#define SPC1_   512           // s per phase-1 block
#define STR1_   36            // u32 row stride (144B: 16B-aligned, shift 4)
#define KVE_    (D_ * D_)     // 1024
#define PKS_    (KVE_ + D_)   // 1056 floats: KV + Ksum

typedef short short8 __attribute__((ext_vector_type(8)));
typedef float f32x4  __attribute__((ext_vector_type(4)));

__device__ __forceinline__ float phi_f(float x) {
    // elu(x)+1 : x>0 -> x+1 ; else exp(x)
    return x > 0.f ? x + 1.f : __expf(x);
}

__device__ __forceinline__ unsigned short bf16_bits(float x) {
    __hip_bfloat16 h = __float2bfloat16(x);   // RNE
    unsigned short u;
    __builtin_memcpy(&u, &h, 2);
    return u;
}

__device__ __forceinline__ void split_bf16(float x, short& hi, short& lo) {
    __hip_bfloat16 hb = __float2bfloat16(x);        // RNE
    const float xh = __bfloat162float(hb);
    __hip_bfloat16 lb = __float2bfloat16(x - xh);
    __builtin_memcpy(&hi, &hb, 2);
    __builtin_memcpy(&lo, &lb, 2);
}

// ---------------- Phase 1: C[32d x 32v] = phiK^T . V per (n,h,chunk) --------
// (R14 version: MFMA, single-bf16 K/V, exact fp32 Ksum, g^=row>>3 swizzle.)
template <bool ATOMIC>
__global__ __launch_bounds__(256) void la_phase1(
    const float* __restrict__ keys, const float* __restrict__ values,
    float* __restrict__ outp /* ATOMIC ? kvfinal[NH][PKS] : partials[NH][CH1][PKS] */)
{
    __shared__ unsigned kS[2][32][STR1_];
    __shared__ unsigned vS[2][32][STR1_];
    __shared__ float red_ks[4][8][4];
    const int nh = blockIdx.x, chunk = blockIdx.y;
    const int n = nh >> 3, h = nh & 7;
    const int t = threadIdx.x, lane = t & 63, w = t >> 6;
    const int row8 = t >> 3;           // 0..31 (s-row within tile half)
    const int c4   = t & 7;            // float4 column (4 d's / 4 v's)
    const int row_l = lane & 15, kg = lane >> 4;
    const int dt = w >> 1, vt = w & 1; // wave's C-tile
    const int odd = row8 & 1;
    const int dv0 = (c4 << 2) + (odd ? 2 : 0);   // first of 2 owned d-rows
    const int s2lo = row8 >> 1;                  // u32 s-pair index (lo half)
    const float* kb = keys   + ((size_t)n * S_) * 256 + h * 32 + (c4 << 2);
    const float* vb = values + ((size_t)n * S_) * 256 + h * 32 + (c4 << 2);
    const int s0 = chunk * SPC1_;

    float ks4[4] = {0.f, 0.f, 0.f, 0.f};
    f32x4 cacc = {0.f, 0.f, 0.f, 0.f};
    float4 Lka, Lkb, Lva, Lvb;

    auto LOADT = [&](int tb) {
        const size_t g0 = ((size_t)(s0 + (tb << 6) + row8)) << 8;
        const size_t g1 = ((size_t)(s0 + (tb << 6) + row8 + 32)) << 8;
        Lka = *(const float4*)(kb + g0);
        Lkb = *(const float4*)(kb + g1);
        Lva = *(const float4*)(vb + g0);
        Lvb = *(const float4*)(vb + g1);
    };
    auto STORE4 = [&](unsigned (*Sarr)[STR1_], const unsigned short* x, int s2) {
        const unsigned mA = (unsigned)x[0] | ((unsigned)x[1] << 16);
        const unsigned mB = (unsigned)x[2] | ((unsigned)x[3] << 16);
        const unsigned pA = __shfl_xor(mA, 8);
        const unsigned pB = __shfl_xor(mB, 8);
        const unsigned m = odd ? mB : mA, p = odd ? pB : pA;
        const unsigned se = odd ? p : m;          // s-even's two bf16 (j, j+1)
        const unsigned so = odd ? m : p;          // s-odd's
        const unsigned w0 = (se & 0xffffu) | ((so & 0xffffu) << 16);
        const unsigned w1 = (se >> 16) | (so & 0xffff0000u);
        Sarr[dv0][4 * ((s2 >> 2) ^ (dv0 >> 3)) + (s2 & 3)]           = w0;
        Sarr[dv0 + 1][4 * ((s2 >> 2) ^ ((dv0 + 1) >> 3)) + (s2 & 3)] = w1;
    };
    auto PROCT = [&](int buf) {
        const float f0[4] = {phi_f(Lka.x), phi_f(Lka.y), phi_f(Lka.z), phi_f(Lka.w)};
        const float f1[4] = {phi_f(Lkb.x), phi_f(Lkb.y), phi_f(Lkb.z), phi_f(Lkb.w)};
        unsigned short kx[4], ky[4], vx[4], vy[4];
#pragma unroll
        for (int j = 0; j < 4; ++j) ks4[j] += f0[j] + f1[j];
        kx[0] = bf16_bits(f0[0]); kx[1] = bf16_bits(f0[1]);
        kx[2] = bf16_bits(f0[2]); kx[3] = bf16_bits(f0[3]);
        ky[0] = bf16_bits(f1[0]); ky[1] = bf16_bits(f1[1]);
        ky[2] = bf16_bits(f1[2]); ky[3] = bf16_bits(f1[3]);
        vx[0] = bf16_bits(Lva.x); vx[1] = bf16_bits(Lva.y);
        vx[2] = bf16_bits(Lva.z); vx[3] = bf16_bits(Lva.w);
        vy[0] = bf16_bits(Lvb.x); vy[1] = bf16_bits(Lvb.y);
        vy[2] = bf16_bits(Lvb.z); vy[3] = bf16_bits(Lvb.w);
        STORE4(kS[buf], kx, s2lo);
        STORE4(kS[buf], ky, s2lo + 16);
        STORE4(vS[buf], vx, s2lo);
        STORE4(vS[buf], vy, s2lo + 16);
    };
    auto FRAG = [&](const unsigned (*Sarr)[STR1_], int row, int sh) -> short8 {
        const int g = ((sh << 2) | kg) ^ (row >> 3);
        union { uint4 u; short8 s; } U;
        U.u = *(const uint4*)&Sarr[row][g << 2];
        return U.s;
    };
    auto COMPT = [&](int buf) {
#pragma unroll
        for (int sh = 0; sh < 2; ++sh) {
            const short8 A = FRAG(kS[buf], (dt << 4) + row_l, sh);
            const short8 B = FRAG(vS[buf], (vt << 4) + row_l, sh);
            cacc = __builtin_amdgcn_mfma_f32_16x16x32_bf16(A, B, cacc, 0, 0, 0);
        }
    };

    LOADT(0);
    PROCT(0);
    __syncthreads();
#pragma unroll
    for (int tb = 0; tb < 8; ++tb) {
        const int cur = tb & 1;
        if (tb < 7) LOADT(tb + 1);       // next-tile loads in flight (T14)
        COMPT(cur);
        if (tb < 7) PROCT(cur ^ 1);      // waits vmcnt, stages other buffer
        __syncthreads();
    }

    // ksum: butterfly over lane bits 3..5 (8 same-c4 lanes), then cross-wave
#pragma unroll
    for (int j = 0; j < 4; ++j) {
        float x = ks4[j];
        x += __shfl_xor(x, 8);
        x += __shfl_xor(x, 16);
        x += __shfl_xor(x, 32);
        ks4[j] = x;
    }
    if (lane < 8) {
#pragma unroll
        for (int j = 0; j < 4; ++j) red_ks[w][lane][j] = ks4[j];
    }
    __syncthreads();

    if (ATOMIC) {
        float* p = outp + (size_t)nh * PKS_;
#pragma unroll
        for (int r = 0; r < 4; ++r) {
            const int dd = (dt << 4) + (kg << 2) + r;   // D row = (lane>>4)*4+reg
            const int vv = (vt << 4) + row_l;           // D col = lane&15
            atomicAdd(&p[dd * D_ + vv], cacc[r]);
        }
        if (t < 32) {
            const float s = red_ks[0][t >> 2][t & 3] + red_ks[1][t >> 2][t & 3]
                          + red_ks[2][t >> 2][t & 3] + red_ks[3][t >> 2][t & 3];
            atomicAdd(&p[KVE_ + t], s);
        }
    } else {
        float* p = outp + ((size_t)nh * CH1_ + chunk) * PKS_;
#pragma unroll
        for (int r = 0; r < 4; ++r) {
            const int dd = (dt << 4) + (kg << 2) + r;
            const int vv = (vt << 4) + row_l;
            p[dd * D_ + vv] = cacc[r];
        }
        if (t < 32) {
            p[KVE_ + t] = red_ks[0][t >> 2][t & 3] + red_ks[1][t >> 2][t & 3]
                        + red_ks[2][t >> 2][t & 3] + red_ks[3][t >> 2][t & 3];
        }
    }
}

// ---- Phase 1b: deterministic 16-way reduce + split-bf16 transpose ----
__global__ __launch_bounds__(256) void la_reduce(
    const float* __restrict__ partials,
    short* __restrict__ kvThi, short* __restrict__ kvTlo,
    float* __restrict__ ksumf)
{
    const int nh = blockIdx.x;
    for (int e = threadIdx.x; e < PKS_; e += 256) {
        const float* p = partials + (size_t)nh * CH1_ * PKS_ + e;
        float s = 0.f;
#pragma unroll
        for (int c = 0; c < CH1_; ++c) s += p[(size_t)c * PKS_];
        if (e < KVE_) {
            const int d = e >> 5, v = e & 31;
            short hi, lo; split_bf16(s, hi, lo);
            kvThi[nh * KVE_ + v * D_ + d] = hi;
            kvTlo[nh * KVE_ + v * D_ + d] = lo;
        } else {
            ksumf[nh * D_ + (e - KVE_)] = s;
        }
    }
}

// atomic-path variant: same split/transpose from a finished kvf buffer
__global__ __launch_bounds__(256) void la_convert(
    const float* __restrict__ kvf,
    short* __restrict__ kvThi, short* __restrict__ kvTlo,
    float* __restrict__ ksumf)
{
    const int nh = blockIdx.x;
    for (int e = threadIdx.x; e < PKS_; e += 256) {
        const float s = kvf[(size_t)nh * PKS_ + e];
        if (e < KVE_) {
            const int d = e >> 5, v = e & 31;
            short hi, lo; split_bf16(s, hi, lo);
            kvThi[nh * KVE_ + v * D_ + d] = hi;
            kvTlo[nh * KVE_ + v * D_ + d] = lo;
        } else {
            ksumf[nh * D_ + (e - KVE_)] = s;
        }
    }
}

__global__ void la_zero(float* __restrict__ p, int nelem) {
    const int i = blockIdx.x * 256 + threadIdx.x;
    if (i < nelem) p[i] = 0.f;
}

// ---------------- Phase 2: MFMA split-bf16, dense-streaming blocks ----------
// Block = 512 threads (8 waves) x 16 rows x ALL 8 h. Stage: full 1KB Q rows
// -> LDS (phi fused), granule swizzle p = g ^ (row&7) (2-way banks, free).
// Wave w computes h = w: A-frags from LDS, B+Ksum from L2-hot kvT, 6 MFMA,
// fp32 dot, same store mapping as R14. Block covers the complete 16KB output
// region -> dense writes in aggregate. 4096 blocks x 8 waves = 32K waves.
__global__ __launch_bounds__(512) void la_phase2(
    const float* __restrict__ queries,
    const short* __restrict__ kvThi, const short* __restrict__ kvTlo,
    const float* __restrict__ ksumf, float* __restrict__ out)
{
    __shared__ float qs[16 * 256];              // 16 KB, swizzled granules
    const int t = threadIdx.x, lane = t & 63, w = t >> 6;
    const size_t rowg0 = (size_t)blockIdx.x * 16;
    const int n  = (int)(rowg0 >> 13);
    const int h  = w;                           // wave's head
    const int nh = n * 8 + h;
    const int row_l = lane & 15;                // A-row / B-col
    const int kg    = lane >> 4;                // k-group: k = kg*8 + e

    // ---- stage 16 rows x 1KB: thread (row = t&15, seg = t>>4) loads 32B ----
    // per-16-lane phase: rows 0..15, same seg -> 16 x 32B at 1KB stride
    // (fills densely across the block); LDS writes at p=(2seg+c)^(row&7):
    // rows vary within phase -> 2-way banks (free).
    {
        const int row = t & 15, seg = t >> 4;   // seg 0..31
        const float* qp = queries + (rowg0 + row) * 256 + seg * 8;
        const float4 a = *(const float4*)(qp);
        const float4 b = *(const float4*)(qp + 4);
        const int p0 = ((seg << 1) | 0) ^ (row & 7);
        const int p1 = ((seg << 1) | 1) ^ (row & 7);
        *(float4*)&qs[row * 256 + p0 * 4] =
            make_float4(phi_f(a.x), phi_f(a.y), phi_f(a.z), phi_f(a.w));
        *(float4*)&qs[row * 256 + p1 * 4] =
            make_float4(phi_f(b.x), phi_f(b.y), phi_f(b.z), phi_f(b.w));
    }

    // ---- B + Ksum for this wave's h (L2-hot; issued before the barrier) ----
    const short* bh = kvThi + (size_t)nh * KVE_;
    const short* bl = kvTlo + (size_t)nh * KVE_;
    const short8 bh0 = *(const short8*)(bh + (row_l     ) * D_ + kg * 8);
    const short8 bh1 = *(const short8*)(bh + (row_l + 16) * D_ + kg * 8);
    const short8 bl0 = *(const short8*)(bl + (row_l     ) * D_ + kg * 8);
    const short8 bl1 = *(const short8*)(bl + (row_l + 16) * D_ + kg * 8);
    const float4 kA = *(const float4*)(ksumf + nh * D_ + kg * 8);
    const float4 kB = *(const float4*)(ksumf + nh * D_ + kg * 8 + 4);

    __syncthreads();

    // ---- A: phiQ[row_l][kg*8..+8] from LDS (granules h*8+kg*2, +1) ----
    float qa[8];
    {
        const int g0 = (h * 8 + kg * 2)     ^ (row_l & 7);
        const int g1 = (h * 8 + kg * 2 + 1) ^ (row_l & 7);
        const float4 f0 = *(const float4*)&qs[row_l * 256 + g0 * 4];
        const float4 f1 = *(const float4*)&qs[row_l * 256 + g1 * 4];
        qa[0] = f0.x; qa[1] = f0.y; qa[2] = f0.z; qa[3] = f0.w;
        qa[4] = f1.x; qa[5] = f1.y; qa[6] = f1.z; qa[7] = f1.w;
    }
    short8 ahi, alo;
#pragma unroll
    for (int e = 0; e < 8; ++e) {
        short hs, ls; split_bf16(qa[e], hs, ls);
        ahi[e] = hs; alo[e] = ls;
    }

    // ---- 6 MFMAs: C = Alo*Bhi + Ahi*Blo + Ahi*Bhi (fp32 accum) ----
    f32x4 c0 = {0.f, 0.f, 0.f, 0.f}, c1 = {0.f, 0.f, 0.f, 0.f};
    c0 = __builtin_amdgcn_mfma_f32_16x16x32_bf16(alo, bh0, c0, 0, 0, 0);
    c0 = __builtin_amdgcn_mfma_f32_16x16x32_bf16(ahi, bl0, c0, 0, 0, 0);
    c0 = __builtin_amdgcn_mfma_f32_16x16x32_bf16(ahi, bh0, c0, 0, 0, 0);
    c1 = __builtin_amdgcn_mfma_f32_16x16x32_bf16(alo, bh1, c1, 0, 0, 0);
    c1 = __builtin_amdgcn_mfma_f32_16x16x32_bf16(ahi, bl1, c1, 0, 0, 0);
    c1 = __builtin_amdgcn_mfma_f32_16x16x32_bf16(ahi, bh1, c1, 0, 0, 0);

    // ---- dot = phiQ . Ksum in fp32; reduce the 4 k-groups per row ----
    float dt = qa[0] * kA.x;
    dt = fmaf(qa[1], kA.y, dt); dt = fmaf(qa[2], kA.z, dt);
    dt = fmaf(qa[3], kA.w, dt); dt = fmaf(qa[4], kB.x, dt);
    dt = fmaf(qa[5], kB.y, dt); dt = fmaf(qa[6], kB.z, dt);
    dt = fmaf(qa[7], kB.w, dt);
    dt += __shfl_xor(dt, 16);
    dt += __shfl_xor(dt, 32);   // all lanes now hold dot[row_l]

    // ---- normalize + store (m89 layout); block covers all 8 h -> dense ----
    float* ob = out + rowg0 * 256 + h * D_ + row_l;
#pragma unroll
    for (int r = 0; r < 4; ++r) {
        const int rowp = kg * 4 + r;
        const float drow = __shfl(dt, rowp);          // lane rowp holds dot[rowp]
        const float z = __builtin_amdgcn_rcpf(drow + 1e-6f);
        ob[(size_t)rowp * 256]      = c0[r] * z;
        ob[(size_t)rowp * 256 + 16] = c1[r] * z;
    }
}

extern "C" void kernel_launch(void* const* d_in, const int* in_sizes, int n_in,
                              void* d_out, int out_size, void* d_ws, size_t ws_size,
                              hipStream_t stream)
{
    const float* queries = (const float*)d_in[0];
    const float* keys    = (const float*)d_in[1];
    const float* values  = (const float*)d_in[2];
    float* out = (float*)d_out;
    float* ws  = (float*)d_ws;

    const size_t partial_elems = (size_t)NH_ * CH1_ * PKS_;    // 1,081,344 floats
    const size_t split_elems   = (size_t)NH_ * KVE_;           // per hi/lo, in shorts
    const size_t split_floats  = split_elems / 2;              // 32,768 float-slots each
    const size_t ksum_floats   = (size_t)NH_ * D_;             // 2,048
    const dim3 blk(256);
    const dim3 blk2(512);
    const int p2_blocks = (N_ * L_) / 16;                      // 4096

    if (ws_size >= (partial_elems + 2 * split_floats + ksum_floats) * sizeof(float)) {
        // deterministic two-stage reduction + split-bf16 conversion
        float* partials = ws;
        short* kvThi = (short*)(ws + partial_elems);
        short* kvTlo = kvThi + split_elems;
        float* ksumf = (float*)(kvTlo + split_elems);
        la_phase1<false><<<dim3(NH_, CH1_), blk, 0, stream>>>(keys, values, partials);
        la_reduce<<<dim3(NH_), blk, 0, stream>>>(partials, kvThi, kvTlo, ksumf);
        la_phase2<<<dim3(p2_blocks), blk2, 0, stream>>>(queries, kvThi, kvTlo, ksumf, out);
    } else {
        // fallback: atomic accumulation into zeroed kvf, then convert
        float* kvf = ws;
        short* kvThi = (short*)(ws + (size_t)NH_ * PKS_);
        short* kvTlo = kvThi + split_elems;
        float* ksumf = (float*)(kvTlo + split_elems);
        const int nz = (int)((size_t)NH_ * PKS_);
        la_zero<<<dim3((nz + 255) / 256), blk, 0, stream>>>(kvf, nz);
        la_phase1<true><<<dim3(NH_, CH1_), blk, 0, stream>>>(keys, values, kvf);
        la_convert<<<dim3(NH_), blk, 0, stream>>>(kvf, kvThi, kvTlo, ksumf);
        la_phase2<<<dim3(p2_blocks), blk2, 0, stream>>>(queries, kvThi, kvTlo, ksumf, out);
    }
}

// Round 19
// 56.703 us; speedup vs baseline: 1.4765x; 1.1096x over previous
//
#include <hip/hip_runtime.h>
#include <hip/hip_bf16.h>

// Linear attention, fp32. N=8, L=S=8192, H=8, D=Dv=32.
// out[n,l,h,v] = (sum_d phiQ[l,d]*KV[d][v]) * 1/(sum_d phiQ[l,d]*Ksum[d] + 1e-6)
// where KV[d][v] = sum_s phiK[s,d]*values[s,v]  (the /S and *S of the reference
// cancel exactly: S is a power of two).
//
// R19: NON-TEMPORAL output stores. Four independent phase2 structures all
// pinned at ~40us (R14/R15/R17/R18) -> read-side exonerated; the invariant
// is the 64MB write stream. Steady-state working set Q+K+V+out = 256MB = L3
// exactly; write-back out-stores allocate 64MB of zero-reuse lines each
// replay, evicting Q/K/V (phase2 FETCH 33-55MB confirms). NT stores bypass
// cache allocation: read set 192MB fits L3 -> Q reads become L3-hits,
// phase1 K/V too. Everything else = R18 (equal-best 62.9us).

#define N_      8
#define L_      8192
#define S_      8192
#define H_      8
#define D_      32
#define NH_     64            // N*H
#define CH1_    16            // phase-1 s-chunks per (n,h)
#define SPC1_   512           // s per phase-1 block
#define STR1_   36            // u32 row stride (144B: 16B-aligned, shift 4)
#define KVE_    (D_ * D_)     // 1024
#define PKS_    (KVE_ + D_)   // 1056 floats: KV + Ksum

typedef short short8 __attribute__((ext_vector_type(8)));
typedef float f32x4  __attribute__((ext_vector_type(4)));

__device__ __forceinline__ float phi_f(float x) {
    // elu(x)+1 : x>0 -> x+1 ; else exp(x)
    return x > 0.f ? x + 1.f : __expf(x);
}

__device__ __forceinline__ unsigned short bf16_bits(float x) {
    __hip_bfloat16 h = __float2bfloat16(x);   // RNE
    unsigned short u;
    __builtin_memcpy(&u, &h, 2);
    return u;
}

__device__ __forceinline__ void split_bf16(float x, short& hi, short& lo) {
    __hip_bfloat16 hb = __float2bfloat16(x);        // RNE
    const float xh = __bfloat162float(hb);
    __hip_bfloat16 lb = __float2bfloat16(x - xh);
    __builtin_memcpy(&hi, &hb, 2);
    __builtin_memcpy(&lo, &lb, 2);
}

// ---------------- Phase 1: C[32d x 32v] = phiK^T . V per (n,h,chunk) --------
// (R14 version: MFMA, single-bf16 K/V, exact fp32 Ksum, g^=row>>3 swizzle.)
template <bool ATOMIC>
__global__ __launch_bounds__(256) void la_phase1(
    const float* __restrict__ keys, const float* __restrict__ values,
    float* __restrict__ outp /* ATOMIC ? kvfinal[NH][PKS] : partials[NH][CH1][PKS] */)
{
    __shared__ unsigned kS[2][32][STR1_];
    __shared__ unsigned vS[2][32][STR1_];
    __shared__ float red_ks[4][8][4];
    const int nh = blockIdx.x, chunk = blockIdx.y;
    const int n = nh >> 3, h = nh & 7;
    const int t = threadIdx.x, lane = t & 63, w = t >> 6;
    const int row8 = t >> 3;           // 0..31 (s-row within tile half)
    const int c4   = t & 7;            // float4 column (4 d's / 4 v's)
    const int row_l = lane & 15, kg = lane >> 4;
    const int dt = w >> 1, vt = w & 1; // wave's C-tile
    const int odd = row8 & 1;
    const int dv0 = (c4 << 2) + (odd ? 2 : 0);   // first of 2 owned d-rows
    const int s2lo = row8 >> 1;                  // u32 s-pair index (lo half)
    const float* kb = keys   + ((size_t)n * S_) * 256 + h * 32 + (c4 << 2);
    const float* vb = values + ((size_t)n * S_) * 256 + h * 32 + (c4 << 2);
    const int s0 = chunk * SPC1_;

    float ks4[4] = {0.f, 0.f, 0.f, 0.f};
    f32x4 cacc = {0.f, 0.f, 0.f, 0.f};
    float4 Lka, Lkb, Lva, Lvb;

    auto LOADT = [&](int tb) {
        const size_t g0 = ((size_t)(s0 + (tb << 6) + row8)) << 8;
        const size_t g1 = ((size_t)(s0 + (tb << 6) + row8 + 32)) << 8;
        Lka = *(const float4*)(kb + g0);
        Lkb = *(const float4*)(kb + g1);
        Lva = *(const float4*)(vb + g0);
        Lvb = *(const float4*)(vb + g1);
    };
    auto STORE4 = [&](unsigned (*Sarr)[STR1_], const unsigned short* x, int s2) {
        const unsigned mA = (unsigned)x[0] | ((unsigned)x[1] << 16);
        const unsigned mB = (unsigned)x[2] | ((unsigned)x[3] << 16);
        const unsigned pA = __shfl_xor(mA, 8);
        const unsigned pB = __shfl_xor(mB, 8);
        const unsigned m = odd ? mB : mA, p = odd ? pB : pA;
        const unsigned se = odd ? p : m;          // s-even's two bf16 (j, j+1)
        const unsigned so = odd ? m : p;          // s-odd's
        const unsigned w0 = (se & 0xffffu) | ((so & 0xffffu) << 16);
        const unsigned w1 = (se >> 16) | (so & 0xffff0000u);
        Sarr[dv0][4 * ((s2 >> 2) ^ (dv0 >> 3)) + (s2 & 3)]           = w0;
        Sarr[dv0 + 1][4 * ((s2 >> 2) ^ ((dv0 + 1) >> 3)) + (s2 & 3)] = w1;
    };
    auto PROCT = [&](int buf) {
        const float f0[4] = {phi_f(Lka.x), phi_f(Lka.y), phi_f(Lka.z), phi_f(Lka.w)};
        const float f1[4] = {phi_f(Lkb.x), phi_f(Lkb.y), phi_f(Lkb.z), phi_f(Lkb.w)};
        unsigned short kx[4], ky[4], vx[4], vy[4];
#pragma unroll
        for (int j = 0; j < 4; ++j) ks4[j] += f0[j] + f1[j];
        kx[0] = bf16_bits(f0[0]); kx[1] = bf16_bits(f0[1]);
        kx[2] = bf16_bits(f0[2]); kx[3] = bf16_bits(f0[3]);
        ky[0] = bf16_bits(f1[0]); ky[1] = bf16_bits(f1[1]);
        ky[2] = bf16_bits(f1[2]); ky[3] = bf16_bits(f1[3]);
        vx[0] = bf16_bits(Lva.x); vx[1] = bf16_bits(Lva.y);
        vx[2] = bf16_bits(Lva.z); vx[3] = bf16_bits(Lva.w);
        vy[0] = bf16_bits(Lvb.x); vy[1] = bf16_bits(Lvb.y);
        vy[2] = bf16_bits(Lvb.z); vy[3] = bf16_bits(Lvb.w);
        STORE4(kS[buf], kx, s2lo);
        STORE4(kS[buf], ky, s2lo + 16);
        STORE4(vS[buf], vx, s2lo);
        STORE4(vS[buf], vy, s2lo + 16);
    };
    auto FRAG = [&](const unsigned (*Sarr)[STR1_], int row, int sh) -> short8 {
        const int g = ((sh << 2) | kg) ^ (row >> 3);
        union { uint4 u; short8 s; } U;
        U.u = *(const uint4*)&Sarr[row][g << 2];
        return U.s;
    };
    auto COMPT = [&](int buf) {
#pragma unroll
        for (int sh = 0; sh < 2; ++sh) {
            const short8 A = FRAG(kS[buf], (dt << 4) + row_l, sh);
            const short8 B = FRAG(vS[buf], (vt << 4) + row_l, sh);
            cacc = __builtin_amdgcn_mfma_f32_16x16x32_bf16(A, B, cacc, 0, 0, 0);
        }
    };

    LOADT(0);
    PROCT(0);
    __syncthreads();
#pragma unroll
    for (int tb = 0; tb < 8; ++tb) {
        const int cur = tb & 1;
        if (tb < 7) LOADT(tb + 1);       // next-tile loads in flight (T14)
        COMPT(cur);
        if (tb < 7) PROCT(cur ^ 1);      // waits vmcnt, stages other buffer
        __syncthreads();
    }

    // ksum: butterfly over lane bits 3..5 (8 same-c4 lanes), then cross-wave
#pragma unroll
    for (int j = 0; j < 4; ++j) {
        float x = ks4[j];
        x += __shfl_xor(x, 8);
        x += __shfl_xor(x, 16);
        x += __shfl_xor(x, 32);
        ks4[j] = x;
    }
    if (lane < 8) {
#pragma unroll
        for (int j = 0; j < 4; ++j) red_ks[w][lane][j] = ks4[j];
    }
    __syncthreads();

    if (ATOMIC) {
        float* p = outp + (size_t)nh * PKS_;
#pragma unroll
        for (int r = 0; r < 4; ++r) {
            const int dd = (dt << 4) + (kg << 2) + r;   // D row = (lane>>4)*4+reg
            const int vv = (vt << 4) + row_l;           // D col = lane&15
            atomicAdd(&p[dd * D_ + vv], cacc[r]);
        }
        if (t < 32) {
            const float s = red_ks[0][t >> 2][t & 3] + red_ks[1][t >> 2][t & 3]
                          + red_ks[2][t >> 2][t & 3] + red_ks[3][t >> 2][t & 3];
            atomicAdd(&p[KVE_ + t], s);
        }
    } else {
        float* p = outp + ((size_t)nh * CH1_ + chunk) * PKS_;
#pragma unroll
        for (int r = 0; r < 4; ++r) {
            const int dd = (dt << 4) + (kg << 2) + r;
            const int vv = (vt << 4) + row_l;
            p[dd * D_ + vv] = cacc[r];
        }
        if (t < 32) {
            p[KVE_ + t] = red_ks[0][t >> 2][t & 3] + red_ks[1][t >> 2][t & 3]
                        + red_ks[2][t >> 2][t & 3] + red_ks[3][t >> 2][t & 3];
        }
    }
}

// ---- Phase 1b: deterministic 16-way reduce + split-bf16 transpose ----
__global__ __launch_bounds__(256) void la_reduce(
    const float* __restrict__ partials,
    short* __restrict__ kvThi, short* __restrict__ kvTlo,
    float* __restrict__ ksumf)
{
    const int nh = blockIdx.x;
    for (int e = threadIdx.x; e < PKS_; e += 256) {
        const float* p = partials + (size_t)nh * CH1_ * PKS_ + e;
        float s = 0.f;
#pragma unroll
        for (int c = 0; c < CH1_; ++c) s += p[(size_t)c * PKS_];
        if (e < KVE_) {
            const int d = e >> 5, v = e & 31;
            short hi, lo; split_bf16(s, hi, lo);
            kvThi[nh * KVE_ + v * D_ + d] = hi;
            kvTlo[nh * KVE_ + v * D_ + d] = lo;
        } else {
            ksumf[nh * D_ + (e - KVE_)] = s;
        }
    }
}

// atomic-path variant: same split/transpose from a finished kvf buffer
__global__ __launch_bounds__(256) void la_convert(
    const float* __restrict__ kvf,
    short* __restrict__ kvThi, short* __restrict__ kvTlo,
    float* __restrict__ ksumf)
{
    const int nh = blockIdx.x;
    for (int e = threadIdx.x; e < PKS_; e += 256) {
        const float s = kvf[(size_t)nh * PKS_ + e];
        if (e < KVE_) {
            const int d = e >> 5, v = e & 31;
            short hi, lo; split_bf16(s, hi, lo);
            kvThi[nh * KVE_ + v * D_ + d] = hi;
            kvTlo[nh * KVE_ + v * D_ + d] = lo;
        } else {
            ksumf[nh * D_ + (e - KVE_)] = s;
        }
    }
}

__global__ void la_zero(float* __restrict__ p, int nelem) {
    const int i = blockIdx.x * 256 + threadIdx.x;
    if (i < nelem) p[i] = 0.f;
}

// ---------------- Phase 2: MFMA split-bf16, dense blocks, NT stores --------
// Block = 512 threads (8 waves) x 16 rows x ALL 8 h; Q staged via LDS (phi
// fused, granule swizzle); wave w computes h=w; output written with
// NON-TEMPORAL stores (no L2/L3 allocation -> Q/K/V stay L3-resident).
__global__ __launch_bounds__(512) void la_phase2(
    const float* __restrict__ queries,
    const short* __restrict__ kvThi, const short* __restrict__ kvTlo,
    const float* __restrict__ ksumf, float* __restrict__ out)
{
    __shared__ float qs[16 * 256];              // 16 KB, swizzled granules
    const int t = threadIdx.x, lane = t & 63, w = t >> 6;
    const size_t rowg0 = (size_t)blockIdx.x * 16;
    const int n  = (int)(rowg0 >> 13);
    const int h  = w;                           // wave's head
    const int nh = n * 8 + h;
    const int row_l = lane & 15;                // A-row / B-col
    const int kg    = lane >> 4;                // k-group: k = kg*8 + e

    // ---- stage 16 rows x 1KB: thread (row = t&15, seg = t>>4) loads 32B ----
    {
        const int row = t & 15, seg = t >> 4;   // seg 0..31
        const float* qp = queries + (rowg0 + row) * 256 + seg * 8;
        const float4 a = *(const float4*)(qp);
        const float4 b = *(const float4*)(qp + 4);
        const int p0 = ((seg << 1) | 0) ^ (row & 7);
        const int p1 = ((seg << 1) | 1) ^ (row & 7);
        *(float4*)&qs[row * 256 + p0 * 4] =
            make_float4(phi_f(a.x), phi_f(a.y), phi_f(a.z), phi_f(a.w));
        *(float4*)&qs[row * 256 + p1 * 4] =
            make_float4(phi_f(b.x), phi_f(b.y), phi_f(b.z), phi_f(b.w));
    }

    // ---- B + Ksum for this wave's h (L2-hot; issued before the barrier) ----
    const short* bh = kvThi + (size_t)nh * KVE_;
    const short* bl = kvTlo + (size_t)nh * KVE_;
    const short8 bh0 = *(const short8*)(bh + (row_l     ) * D_ + kg * 8);
    const short8 bh1 = *(const short8*)(bh + (row_l + 16) * D_ + kg * 8);
    const short8 bl0 = *(const short8*)(bl + (row_l     ) * D_ + kg * 8);
    const short8 bl1 = *(const short8*)(bl + (row_l + 16) * D_ + kg * 8);
    const float4 kA = *(const float4*)(ksumf + nh * D_ + kg * 8);
    const float4 kB = *(const float4*)(ksumf + nh * D_ + kg * 8 + 4);

    __syncthreads();

    // ---- A: phiQ[row_l][kg*8..+8] from LDS (granules h*8+kg*2, +1) ----
    float qa[8];
    {
        const int g0 = (h * 8 + kg * 2)     ^ (row_l & 7);
        const int g1 = (h * 8 + kg * 2 + 1) ^ (row_l & 7);
        const float4 f0 = *(const float4*)&qs[row_l * 256 + g0 * 4];
        const float4 f1 = *(const float4*)&qs[row_l * 256 + g1 * 4];
        qa[0] = f0.x; qa[1] = f0.y; qa[2] = f0.z; qa[3] = f0.w;
        qa[4] = f1.x; qa[5] = f1.y; qa[6] = f1.z; qa[7] = f1.w;
    }
    short8 ahi, alo;
#pragma unroll
    for (int e = 0; e < 8; ++e) {
        short hs, ls; split_bf16(qa[e], hs, ls);
        ahi[e] = hs; alo[e] = ls;
    }

    // ---- 6 MFMAs: C = Alo*Bhi + Ahi*Blo + Ahi*Bhi (fp32 accum) ----
    f32x4 c0 = {0.f, 0.f, 0.f, 0.f}, c1 = {0.f, 0.f, 0.f, 0.f};
    c0 = __builtin_amdgcn_mfma_f32_16x16x32_bf16(alo, bh0, c0, 0, 0, 0);
    c0 = __builtin_amdgcn_mfma_f32_16x16x32_bf16(ahi, bl0, c0, 0, 0, 0);
    c0 = __builtin_amdgcn_mfma_f32_16x16x32_bf16(ahi, bh0, c0, 0, 0, 0);
    c1 = __builtin_amdgcn_mfma_f32_16x16x32_bf16(alo, bh1, c1, 0, 0, 0);
    c1 = __builtin_amdgcn_mfma_f32_16x16x32_bf16(ahi, bl1, c1, 0, 0, 0);
    c1 = __builtin_amdgcn_mfma_f32_16x16x32_bf16(ahi, bh1, c1, 0, 0, 0);

    // ---- dot = phiQ . Ksum in fp32; reduce the 4 k-groups per row ----
    float dt = qa[0] * kA.x;
    dt = fmaf(qa[1], kA.y, dt); dt = fmaf(qa[2], kA.z, dt);
    dt = fmaf(qa[3], kA.w, dt); dt = fmaf(qa[4], kB.x, dt);
    dt = fmaf(qa[5], kB.y, dt); dt = fmaf(qa[6], kB.z, dt);
    dt = fmaf(qa[7], kB.w, dt);
    dt += __shfl_xor(dt, 16);
    dt += __shfl_xor(dt, 32);   // all lanes now hold dot[row_l]

    // ---- normalize + NT store (m89 layout); no cache allocation ----
    float* ob = out + rowg0 * 256 + h * D_ + row_l;
#pragma unroll
    for (int r = 0; r < 4; ++r) {
        const int rowp = kg * 4 + r;
        const float drow = __shfl(dt, rowp);          // lane rowp holds dot[rowp]
        const float z = __builtin_amdgcn_rcpf(drow + 1e-6f);
        __builtin_nontemporal_store(c0[r] * z, &ob[(size_t)rowp * 256]);
        __builtin_nontemporal_store(c1[r] * z, &ob[(size_t)rowp * 256 + 16]);
    }
}

extern "C" void kernel_launch(void* const* d_in, const int* in_sizes, int n_in,
                              void* d_out, int out_size, void* d_ws, size_t ws_size,
                              hipStream_t stream)
{
    const float* queries = (const float*)d_in[0];
    const float* keys    = (const float*)d_in[1];
    const float* values  = (const float*)d_in[2];
    float* out = (float*)d_out;
    float* ws  = (float*)d_ws;

    const size_t partial_elems = (size_t)NH_ * CH1_ * PKS_;    // 1,081,344 floats
    const size_t split_elems   = (size_t)NH_ * KVE_;           // per hi/lo, in shorts
    const size_t split_floats  = split_elems / 2;              // 32,768 float-slots each
    const size_t ksum_floats   = (size_t)NH_ * D_;             // 2,048
    const dim3 blk(256);
    const dim3 blk2(512);
    const int p2_blocks = (N_ * L_) / 16;                      // 4096

    if (ws_size >= (partial_elems + 2 * split_floats + ksum_floats) * sizeof(float)) {
        // deterministic two-stage reduction + split-bf16 conversion
        float* partials = ws;
        short* kvThi = (short*)(ws + partial_elems);
        short* kvTlo = kvThi + split_elems;
        float* ksumf = (float*)(kvTlo + split_elems);
        la_phase1<false><<<dim3(NH_, CH1_), blk, 0, stream>>>(keys, values, partials);
        la_reduce<<<dim3(NH_), blk, 0, stream>>>(partials, kvThi, kvTlo, ksumf);
        la_phase2<<<dim3(p2_blocks), blk2, 0, stream>>>(queries, kvThi, kvTlo, ksumf, out);
    } else {
        // fallback: atomic accumulation into zeroed kvf, then convert
        float* kvf = ws;
        short* kvThi = (short*)(ws + (size_t)NH_ * PKS_);
        short* kvTlo = kvThi + split_elems;
        float* ksumf = (float*)(kvTlo + split_elems);
        const int nz = (int)((size_t)NH_ * PKS_);
        la_zero<<<dim3((nz + 255) / 256), blk, 0, stream>>>(kvf, nz);
        la_phase1<true><<<dim3(NH_, CH1_), blk, 0, stream>>>(keys, values, kvf);
        la_convert<<<dim3(NH_), blk, 0, stream>>>(kvf, kvThi, kvTlo, ksumf);
        la_phase2<<<dim3(p2_blocks), blk2, 0, stream>>>(queries, kvThi, kvTlo, ksumf, out);
    }
}